// Round 7
// baseline (267.655 us; speedup 1.0000x reference)
//
#include <hip/hip_runtime.h>
#include <stdint.h>

// DCNv2 fused forward (B=8, C=256, H=W=64, OC=256, 3x3, pad=1, stride=1, DG=1)
// R12: tap-batched v7. EXACT v7 sync semantics (write-all -> barrier ->
// read-all -> barrier), coarsened from 1 k-step to 8 k-steps (one tap) per
// phase pair: 9 barrier pairs instead of 72.
//  - GEN phase: coords once per tap; 8 chunks of corners loaded (register
//    double-buffer WITHIN the phase), bilinear+fp16-pack+ds_write to an
//    8-step Bs region (66 KB LDS, 2 blocks/CU).
//  - MFMA phase: per step, A-fragments from bw2 (register double-buffer
//    WITHIN the phase) + ds_read B + 48 MFMAs; 384 MFMAs per phase.
//  - NOTHING is consumed across a barrier that wasn't already proven in v7
//    (R10/R11 post-mortem: cross-phase prefetch consumption = cursed).
// fp16 hi/lo 3-product numerics (weights x64, epilogue /64) — R8/R9-proven.

typedef __attribute__((ext_vector_type(8))) _Float16 half8;
typedef __attribute__((ext_vector_type(2))) __fp16 fp16x2;
typedef __attribute__((ext_vector_type(4))) float floatx4;
typedef __attribute__((ext_vector_type(4))) unsigned int uintx4;

#define MFMA16(A, B, C) __builtin_amdgcn_mfma_f32_16x16x32_f16(A, B, C, 0, 0, 0)

__device__ __forceinline__ void split_f16_bits(float v, unsigned int& h, unsigned int& l) {
    _Float16 hf = (_Float16)v;               // v_cvt_f16_f32 (RNE)
    float hff = (float)hf;                   // exact
    _Float16 lf = (_Float16)(v - hff);       // residual, RNE
    union { _Float16 f; unsigned short s; } a, b;
    a.f = hf; b.f = lf;
    h = a.s; l = b.s;
}

__device__ __forceinline__ void split_pack8(const float* vals, uintx4& pkH, uintx4& pkL) {
#pragma unroll
    for (int p = 0; p < 4; p++) {
        float v0 = vals[2 * p], v1 = vals[2 * p + 1];
        fp16x2 h = __builtin_amdgcn_cvt_pkrtz(v0, v1);      // RTZ hi pair
        float h0 = (float)h[0], h1 = (float)h[1];           // exact back-convert
        fp16x2 l = __builtin_amdgcn_cvt_pkrtz(v0 - h0, v1 - h1);  // lo pair
        union { fp16x2 v; unsigned int u; } ch, cl;
        ch.v = h; cl.v = l;
        pkH[p] = ch.u;
        pkL[p] = cl.u;
    }
}

__device__ __forceinline__ void mk_coords(int tap, int ho, int wo,
    float offy, float offx, float m,
    int& yx00, int& yx01, int& yx10, int& yx11,
    float& w00, float& w01, float& w10, float& w11) {
    float py = (float)(tap / 3) + (float)(ho - 1) + offy;
    float px = (float)(tap % 3) + (float)(wo - 1) + offx;
    float y0f = floorf(py), x0f = floorf(px);
    float wy1 = py - y0f, wx1 = px - x0f;
    float wy0 = 1.f - wy1, wx0 = 1.f - wx1;
    int y0 = (int)y0f, x0 = (int)x0f, y1 = y0 + 1, x1 = x0 + 1;
    bool vy0 = (y0 >= 0) && (y0 < 64), vy1 = (y1 >= 0) && (y1 < 64);
    bool vx0 = (x0 >= 0) && (x0 < 64), vx1 = (x1 >= 0) && (x1 < 64);
    int cy0 = min(max(y0, 0), 63), cy1 = min(max(y1, 0), 63);
    int cx0 = min(max(x0, 0), 63), cx1 = min(max(x1, 0), 63);
    yx00 = cy0 * 64 + cx0; yx01 = cy0 * 64 + cx1;
    yx10 = cy1 * 64 + cx0; yx11 = cy1 * 64 + cx1;
    w00 = wy0 * wx0 * m * ((vy0 && vx0) ? 1.f : 0.f);
    w01 = wy0 * wx1 * m * ((vy0 && vx1) ? 1.f : 0.f);
    w10 = wy1 * wx0 * m * ((vy1 && vx0) ? 1.f : 0.f);
    w11 = wy1 * wx1 * m * ((vy1 && vx1) ? 1.f : 0.f);
}

// ---- prep: x (8,256,64,64) f32 -> xtf (8,4096,256) f32, tiled transpose ----
__global__ __launch_bounds__(256) void k_prep_xt(const float* __restrict__ x,
                                                 float* __restrict__ xtf) {
    __shared__ float T[64][65];
    const int blk = blockIdx.x;       // 2048
    const int b = blk >> 8;
    const int ct = (blk >> 6) & 3;
    const int tt = blk & 63;
    const int t = threadIdx.x;
    const int jj = t & 63, i4 = t >> 6;
    const float* xb = x + ((size_t)b << 20);
#pragma unroll 4
    for (int ii = 0; ii < 16; ii++) {
        int i = ii * 4 + i4;
        T[i][jj] = xb[((size_t)(ct * 64 + i) << 12) + tt * 64 + jj];
    }
    __syncthreads();
    float* ob = xtf + ((size_t)b << 20);
#pragma unroll 4
    for (int ii = 0; ii < 16; ii++) {
        int jo = ii * 4 + i4;
        ob[((size_t)(tt * 64 + jo) << 8) + ct * 64 + jj] = T[jj][jo];
    }
}

// ---- prep: weight*64 -> bw2[step72][hl2][chunk4][oc256][8k] fp16 ----
__global__ __launch_bounds__(256) void k_prep_w2(const float* __restrict__ w,
                                                 unsigned short* __restrict__ bw2) {
    int tid = blockIdx.x * 256 + threadIdx.x;   // 72*16384
    int j = tid & 7;
    int oc = (tid >> 3) & 255;
    int c = (tid >> 11) & 3;
    int hl = (tid >> 13) & 1;
    int step = tid >> 14;
    int ktap = step >> 3;
    int ch = ((step & 7) << 5) + (c << 3) + j;
    float v = w[oc * 2304 + ch * 9 + ktap] * 64.f;
    unsigned int h, l;
    split_f16_bits(v, h, l);
    bw2[tid] = (unsigned short)(hl ? l : h);
}

// ---- main (tap-batched, v7 sync semantics) ----
__global__ __launch_bounds__(256, 2) void k_dcn_v10(
    const float* __restrict__ offset,  // (8,18,64,64)
    const float* __restrict__ mask,    // (8,9,64,64)
    const float* __restrict__ bias,    // (256,)
    const float* __restrict__ xtf,     // (8,4096,256) f32
    const unsigned short* __restrict__ bw2,  // (72,2,4,256,8) fp16
    float* __restrict__ out)           // (8,256,64,64)
{
    // B region: [step8][hl2(+2112)][chunk4(stride 528)][pos64][8] = 8*4224 ush = 66 KB
    __shared__ __align__(16) unsigned short Bs[8 * 4224];

    const int t = threadIdx.x;
    const int tile = blockIdx.x;   // 512
    const int b = tile & 7;        // XCD/L2 locality
    const int ho = tile >> 3;      // 0..63

    const int lane = t & 63, wid = t >> 6, quad = lane >> 4, l15 = lane & 15;
    const int gpos = t >> 2, gseg = t & 3;
    const int wo = gpos;
    const int spos = (ho << 6) + wo;
    const float* xb = xtf + ((size_t)b << 20);

    // A fragment base (ush): [step][hl][chunk=quad][oc][8], oc = wid*64 + i*16 + l15
    const unsigned short* aBase = bw2 + quad * 2048 + (((wid << 6) + l15) << 3);

    floatx4 acc[4][4];
#pragma unroll
    for (int i = 0; i < 4; i++)
#pragma unroll
        for (int j = 0; j < 4; j++) acc[i][j] = (floatx4){0.f, 0.f, 0.f, 0.f};

    half8 aCur[8], aNxt[8];        // [0..3]=hi rows, [4..7]=lo rows
    floatx4 crnA[8], crnB[8];      // in-phase corner double-buffer
    int yx00, yx01, yx10, yx11;
    float w00, w01, w10, w11;

#define LOAD_A(DST, KK) {                                                   \
    const unsigned short* ap = aBase + (size_t)(KK) * 16384;                \
    _Pragma("unroll")                                                       \
    for (int i = 0; i < 4; i++) {                                           \
        DST[i]     = *(const half8*)(ap + i * 128);                         \
        DST[4 + i] = *(const half8*)(ap + 8192 + i * 128);                  \
    } }

// corners for chunk JS (0..7) of the current tap
#define LOAD_CRN(DST, JS) {                                                 \
    const int cb = ((JS) << 5) + (gseg << 3);                               \
    const float* p00 = xb + ((size_t)yx00 << 8) + cb;                       \
    const float* p01 = xb + ((size_t)yx01 << 8) + cb;                       \
    const float* p10 = xb + ((size_t)yx10 << 8) + cb;                       \
    const float* p11 = xb + ((size_t)yx11 << 8) + cb;                       \
    DST[0] = *(const floatx4*)p00; DST[1] = *(const floatx4*)(p00 + 4);     \
    DST[2] = *(const floatx4*)p01; DST[3] = *(const floatx4*)(p01 + 4);     \
    DST[4] = *(const floatx4*)p10; DST[5] = *(const floatx4*)(p10 + 4);     \
    DST[6] = *(const floatx4*)p11; DST[7] = *(const floatx4*)(p11 + 4); }

#define GEN_WRITE(CRN, JS) {                                                \
    float vals[8];                                                          \
    _Pragma("unroll")                                                       \
    for (int q = 0; q < 4; q++) {                                           \
        vals[q]     = w00 * CRN[0][q] + w01 * CRN[2][q] +                   \
                      w10 * CRN[4][q] + w11 * CRN[6][q];                    \
        vals[4 + q] = w00 * CRN[1][q] + w01 * CRN[3][q] +                   \
                      w10 * CRN[5][q] + w11 * CRN[7][q];                    \
    }                                                                       \
    uintx4 pkH, pkL;                                                        \
    split_pack8(vals, pkH, pkL);                                            \
    unsigned short* bp = Bs + (JS) * 4224 + gseg * 528 + (gpos << 3);       \
    *(uintx4*)bp = pkH;                                                     \
    *(uintx4*)(bp + 2112) = pkL; }

#define MFMA_STEP(JS, AREG) {                                               \
    const unsigned short* Bp = Bs + (JS) * 4224 + quad * 528;               \
    half8 bH[4], bL[4];                                                     \
    _Pragma("unroll")                                                       \
    for (int j = 0; j < 4; j++) {                                           \
        const int ro = ((j << 4) + l15) << 3;                               \
        bH[j] = *(const half8*)(Bp + ro);                                   \
        bL[j] = *(const half8*)(Bp + 2112 + ro);                            \
    }                                                                       \
    _Pragma("unroll")                                                       \
    for (int i = 0; i < 4; i++)                                             \
    _Pragma("unroll")                                                       \
        for (int j = 0; j < 4; j++) {                                       \
            acc[i][j] = MFMA16(AREG[i], bH[j], acc[i][j]);                  \
            acc[i][j] = MFMA16(AREG[4 + i], bH[j], acc[i][j]);              \
            acc[i][j] = MFMA16(AREG[i], bL[j], acc[i][j]);                  \
        } }

    for (int tap = 0; tap < 9; ++tap) {
        // ---- GEN phase: coords + 8 chunks of bilinear -> Bs[0..7] ----
        {
            float oy = offset[((size_t)(b * 18 + 2 * tap) << 12) + spos];
            float ox = offset[((size_t)(b * 18 + 2 * tap + 1) << 12) + spos];
            float mm = mask[((size_t)(b * 9 + tap) << 12) + spos];
            mk_coords(tap, ho, wo, oy, ox, mm,
                      yx00, yx01, yx10, yx11, w00, w01, w10, w11);
        }
        LOAD_CRN(crnA, 0);
#pragma unroll
        for (int js = 0; js < 8; js += 2) {
            LOAD_CRN(crnB, js + 1);            // always valid (js+1 <= 7)
            GEN_WRITE(crnA, js);
            if (js + 2 < 8) LOAD_CRN(crnA, js + 2);
            GEN_WRITE(crnB, js + 1);
        }
        __syncthreads();                       // all Bs[0..7] visible

        // ---- MFMA phase: 8 steps, A in-phase register double-buffer ----
        const int kb = tap << 3;
        LOAD_A(aCur, kb);
#pragma unroll
        for (int js = 0; js < 8; js += 2) {
            LOAD_A(aNxt, kb + js + 1);         // always valid (js+1 <= 7)
            MFMA_STEP(js, aCur);
            if (js + 2 < 8) LOAD_A(aCur, kb + js + 2);
            MFMA_STEP(js + 1, aNxt);
        }
        __syncthreads();                       // all reads done before next GEN
    }

    // ---- epilogue: C/D col=lane&15 -> pos, row=quad*4+r -> oc; undo x64 ----
    float* outb = out + ((size_t)b << 20);
    const int posbase = ho << 6;
#pragma unroll
    for (int i = 0; i < 4; i++) {
        const int ocb = (wid << 6) + (i << 4) + (quad << 2);
#pragma unroll
        for (int r = 0; r < 4; r++) {
            const float bv = bias[ocb + r];
#pragma unroll
            for (int j = 0; j < 4; j++) {
                const int pos = posbase + (j << 4) + l15;
                outb[((size_t)(ocb + r) << 12) + pos] = acc[i][j][r] * 0.015625f + bv;
            }
        }
    }
#undef LOAD_A
#undef LOAD_CRN
#undef GEN_WRITE
#undef MFMA_STEP
}

// ---- fallback (no workspace): R8-proven, unchanged ----
__global__ __launch_bounds__(256, 2) void k_dcn_fb(
    const float* __restrict__ x, const float* __restrict__ offset,
    const float* __restrict__ mask, const float* __restrict__ weight,
    const float* __restrict__ bias, float* __restrict__ out)
{
    __shared__ __align__(16) unsigned short AsH[256 * 40];
    __shared__ __align__(16) unsigned short AsL[256 * 40];
    __shared__ __align__(16) unsigned short BsH[64 * 40];
    __shared__ __align__(16) unsigned short BsL[64 * 40];
    __shared__ int cY[64][4];
    __shared__ float cW[64][4];

    const int t = threadIdx.x;
    const int tile = blockIdx.x;   // 512
    const int b = tile >> 6;
    const int ho = tile & 63;
    const int lane = t & 63, wid = t >> 6, quad = lane >> 4, l15 = lane & 15;
    const int gpos = t >> 2, gseg = t & 3;

    floatx4 acc[4][4];
#pragma unroll
    for (int i = 0; i < 4; i++)
#pragma unroll
        for (int j = 0; j < 4; j++) acc[i][j] = (floatx4){0.f, 0.f, 0.f, 0.f};

    for (int ktap = 0; ktap < 9; ++ktap) {
        __syncthreads();
        if (t < 64) {
            int wo = t;
            int spos = (ho << 6) + wo;
            float offy = offset[(((size_t)(b * 18 + 2 * ktap)) << 12) + spos];
            float offx = offset[(((size_t)(b * 18 + 2 * ktap + 1)) << 12) + spos];
            float m = mask[(((size_t)(b * 9 + ktap)) << 12) + spos];
            int c0, c1, c2, c3; float u0, u1, u2, u3;
            mk_coords(ktap, ho, wo, offy, offx, m, c0, c1, c2, c3, u0, u1, u2, u3);
            cY[t][0] = c0; cY[t][1] = c1; cY[t][2] = c2; cY[t][3] = c3;
            cW[t][0] = u0; cW[t][1] = u1; cW[t][2] = u2; cW[t][3] = u3;
        }
        __syncthreads();
        const int yx00 = cY[gpos][0], yx01 = cY[gpos][1];
        const int yx10 = cY[gpos][2], yx11 = cY[gpos][3];
        const float w00 = cW[gpos][0], w01 = cW[gpos][1];
        const float w10 = cW[gpos][2], w11 = cW[gpos][3];

        for (int cs = 0; cs < 8; ++cs) {
            const int c0 = cs << 5;
            {
                const float* wp = weight + (size_t)t * 2304 + (size_t)c0 * 9 + ktap;
#pragma unroll
                for (int kj = 0; kj < 32; kj += 2) {
                    unsigned int h0, l0u, h1, l1u;
                    split_f16_bits(wp[kj * 9] * 64.f, h0, l0u);
                    split_f16_bits(wp[kj * 9 + 9] * 64.f, h1, l1u);
                    *(unsigned int*)&AsH[t * 40 + kj] = h0 | (h1 << 16);
                    *(unsigned int*)&AsL[t * 40 + kj] = l0u | (l1u << 16);
                }
            }
            {
                const int cb = c0 + (gseg << 3);
                const float* xg = x + ((size_t)b << 20);
                float vals[8];
#pragma unroll
                for (int j = 0; j < 8; j++) {
                    const float* xc = xg + ((size_t)(cb + j) << 12);
                    vals[j] = w00 * xc[yx00] + w01 * xc[yx01] +
                              w10 * xc[yx10] + w11 * xc[yx11];
                }
                uintx4 pkH, pkL;
                split_pack8(vals, pkH, pkL);
                *(uintx4*)&BsH[gpos * 40 + (gseg << 3)] = pkH;
                *(uintx4*)&BsL[gpos * 40 + (gseg << 3)] = pkL;
            }
            __syncthreads();
            half8 aH[4], aL[4], bH[4], bL[4];
#pragma unroll
            for (int i = 0; i < 4; i++) {
                const int rowA = (wid << 6) + (i << 4) + l15;
                aH[i] = *(const half8*)&AsH[rowA * 40 + (quad << 3)];
                aL[i] = *(const half8*)&AsL[rowA * 40 + (quad << 3)];
            }
#pragma unroll
            for (int j = 0; j < 4; j++) {
                const int rowB = (j << 4) + l15;
                bH[j] = *(const half8*)&BsH[rowB * 40 + (quad << 3)];
                bL[j] = *(const half8*)&BsL[rowB * 40 + (quad << 3)];
            }
#pragma unroll
            for (int i = 0; i < 4; i++)
#pragma unroll
                for (int j = 0; j < 4; j++) {
                    acc[i][j] = MFMA16(aH[i], bH[j], acc[i][j]);
                    acc[i][j] = MFMA16(aL[i], bH[j], acc[i][j]);
                    acc[i][j] = MFMA16(aH[i], bL[j], acc[i][j]);
                }
            __syncthreads();
        }
    }
    float* outb = out + ((size_t)b << 20);
    const int posbase = ho << 6;
#pragma unroll
    for (int i = 0; i < 4; i++) {
        const int ocb = (wid << 6) + (i << 4) + (quad << 2);
#pragma unroll
        for (int r = 0; r < 4; r++) {
            const float bv = bias[ocb + r];
#pragma unroll
            for (int j = 0; j < 4; j++) {
                const int pos = posbase + (j << 4) + l15;
                outb[((size_t)(ocb + r) << 12) + pos] = acc[i][j][r] * 0.015625f + bv;
            }
        }
    }
}

extern "C" void kernel_launch(void* const* d_in, const int* in_sizes, int n_in,
                              void* d_out, int out_size, void* d_ws, size_t ws_size,
                              hipStream_t stream) {
    const float* x      = (const float*)d_in[0];
    const float* offset = (const float*)d_in[1];
    const float* mask   = (const float*)d_in[2];
    const float* weight = (const float*)d_in[3];
    const float* bias   = (const float*)d_in[4];
    float* out = (float*)d_out;

    const size_t xtf_bytes = (size_t)8 * 4096 * 256 * 4;       // 32 MB
    const size_t bw2_elems = (size_t)72 * 16384;               // 1179648 ush
    const size_t need = xtf_bytes + bw2_elems * 2;             // ~34.25 MB

    if (ws_size >= need) {
        float* xtf = (float*)d_ws;
        unsigned short* bw2 = (unsigned short*)((char*)d_ws + xtf_bytes);
        k_prep_xt<<<2048, 256, 0, stream>>>(x, xtf);
        k_prep_w2<<<(int)(bw2_elems / 256), 256, 0, stream>>>(weight, bw2);
        k_dcn_v10<<<512, 256, 0, stream>>>(offset, mask, bias, xtf, bw2, out);
    } else {
        k_dcn_fb<<<512, 256, 0, stream>>>(x, offset, mask, weight, bias, out);
    }
}

// Round 9
// 230.004 us; speedup vs baseline: 1.1637x; 1.1637x over previous
//
#include <hip/hip_runtime.h>
#include <stdint.h>

// DCNv2 fused forward (B=8, C=256, H=W=64, OC=256, 3x3, pad=1, stride=1, DG=1)
// R14 (v11 + do-while macro fix): chunk-major phases. Outer loop c=0..7:
//   GEN: 9 taps' bilinear at column-chunk c -> Bs[9 slots] (in-phase 1-deep
//        corner pipeline; coords recomputed per phase from 27 prologue regs)
//   barrier; MFMA: 9 steps (step = tap*8+c), A 1-deep in-phase; barrier.
// Why: v10 post-mortem — tap-major batching read full 1KB rows per phase,
// blowing the 4MB/XCD L2 (FETCH +63%, corners fell to HBM latency). Chunk-major
// keeps v7's 32B column streaming (~400KB/XCD per phase) AND cuts barrier
// pairs 72 -> 9. All load->use within straight-line phase code (proven-safe
// envelope: no loop-backedge-carried VMEM registers — R5/R10/R11 all violated
// this and failed; R8/R9/R12 respect it and pass).
// fp16 hi/lo 3-product numerics (weights x64, epilogue /64) — R8/R9-proven.

typedef __attribute__((ext_vector_type(8))) _Float16 half8;
typedef __attribute__((ext_vector_type(2))) __fp16 fp16x2;
typedef __attribute__((ext_vector_type(4))) float floatx4;
typedef __attribute__((ext_vector_type(4))) unsigned int uintx4;

#define MFMA16(A, B, C) __builtin_amdgcn_mfma_f32_16x16x32_f16(A, B, C, 0, 0, 0)

__device__ __forceinline__ void split_f16_bits(float v, unsigned int& h, unsigned int& l) {
    _Float16 hf = (_Float16)v;               // v_cvt_f16_f32 (RNE)
    float hff = (float)hf;                   // exact
    _Float16 lf = (_Float16)(v - hff);       // residual, RNE
    union { _Float16 f; unsigned short s; } a, b;
    a.f = hf; b.f = lf;
    h = a.s; l = b.s;
}

__device__ __forceinline__ void split_pack8(const float* vals, uintx4& pkH, uintx4& pkL) {
#pragma unroll
    for (int p = 0; p < 4; p++) {
        float v0 = vals[2 * p], v1 = vals[2 * p + 1];
        fp16x2 h = __builtin_amdgcn_cvt_pkrtz(v0, v1);      // RTZ hi pair
        float h0 = (float)h[0], h1 = (float)h[1];           // exact back-convert
        fp16x2 l = __builtin_amdgcn_cvt_pkrtz(v0 - h0, v1 - h1);  // lo pair
        union { fp16x2 v; unsigned int u; } ch, cl;
        ch.v = h; cl.v = l;
        pkH[p] = ch.u;
        pkL[p] = cl.u;
    }
}

__device__ __forceinline__ void mk_coords(int tap, int ho, int wo,
    float offy, float offx, float m,
    int& yx00, int& yx01, int& yx10, int& yx11,
    float& w00, float& w01, float& w10, float& w11) {
    float py = (float)(tap / 3) + (float)(ho - 1) + offy;
    float px = (float)(tap % 3) + (float)(wo - 1) + offx;
    float y0f = floorf(py), x0f = floorf(px);
    float wy1 = py - y0f, wx1 = px - x0f;
    float wy0 = 1.f - wy1, wx0 = 1.f - wx1;
    int y0 = (int)y0f, x0 = (int)x0f, y1 = y0 + 1, x1 = x0 + 1;
    bool vy0 = (y0 >= 0) && (y0 < 64), vy1 = (y1 >= 0) && (y1 < 64);
    bool vx0 = (x0 >= 0) && (x0 < 64), vx1 = (x1 >= 0) && (x1 < 64);
    int cy0 = min(max(y0, 0), 63), cy1 = min(max(y1, 0), 63);
    int cx0 = min(max(x0, 0), 63), cx1 = min(max(x1, 0), 63);
    yx00 = cy0 * 64 + cx0; yx01 = cy0 * 64 + cx1;
    yx10 = cy1 * 64 + cx0; yx11 = cy1 * 64 + cx1;
    w00 = wy0 * wx0 * m * ((vy0 && vx0) ? 1.f : 0.f);
    w01 = wy0 * wx1 * m * ((vy0 && vx1) ? 1.f : 0.f);
    w10 = wy1 * wx0 * m * ((vy1 && vx0) ? 1.f : 0.f);
    w11 = wy1 * wx1 * m * ((vy1 && vx1) ? 1.f : 0.f);
}

// ---- prep: x (8,256,64,64) f32 -> xtf (8,4096,256) f32, tiled transpose ----
__global__ __launch_bounds__(256) void k_prep_xt(const float* __restrict__ x,
                                                 float* __restrict__ xtf) {
    __shared__ float T[64][65];
    const int blk = blockIdx.x;       // 2048
    const int b = blk >> 8;
    const int ct = (blk >> 6) & 3;
    const int tt = blk & 63;
    const int t = threadIdx.x;
    const int jj = t & 63, i4 = t >> 6;
    const float* xb = x + ((size_t)b << 20);
#pragma unroll 4
    for (int ii = 0; ii < 16; ii++) {
        int i = ii * 4 + i4;
        T[i][jj] = xb[((size_t)(ct * 64 + i) << 12) + tt * 64 + jj];
    }
    __syncthreads();
    float* ob = xtf + ((size_t)b << 20);
#pragma unroll 4
    for (int ii = 0; ii < 16; ii++) {
        int jo = ii * 4 + i4;
        ob[((size_t)(tt * 64 + jo) << 8) + ct * 64 + jj] = T[jj][jo];
    }
}

// ---- prep: weight*64 -> bw2[step72][hl2][chunk4][oc256][8k] fp16 ----
__global__ __launch_bounds__(256) void k_prep_w2(const float* __restrict__ w,
                                                 unsigned short* __restrict__ bw2) {
    int tid = blockIdx.x * 256 + threadIdx.x;   // 72*16384
    int j = tid & 7;
    int oc = (tid >> 3) & 255;
    int c = (tid >> 11) & 3;
    int hl = (tid >> 13) & 1;
    int step = tid >> 14;
    int ktap = step >> 3;
    int ch = ((step & 7) << 5) + (c << 3) + j;
    float v = w[oc * 2304 + ch * 9 + ktap] * 64.f;
    unsigned int h, l;
    split_f16_bits(v, h, l);
    bw2[tid] = (unsigned short)(hl ? l : h);
}

// ---- main (chunk-major phases, in-phase pipelining only) ----
__global__ __launch_bounds__(256, 2) void k_dcn_v11(
    const float* __restrict__ offset,  // (8,18,64,64)
    const float* __restrict__ mask,    // (8,9,64,64)
    const float* __restrict__ bias,    // (256,)
    const float* __restrict__ xtf,     // (8,4096,256) f32
    const unsigned short* __restrict__ bw2,  // (72,2,4,256,8) fp16
    float* __restrict__ out)           // (8,256,64,64)
{
    // B region: [slot9(tap)][hl2(+2112)][chunk4(stride 528)][pos64][8] = 76 KB
    __shared__ __align__(16) unsigned short Bs[9 * 4224];

    const int t = threadIdx.x;
    const int tile = blockIdx.x;   // 512
    const int b = tile & 7;        // XCD/L2 locality
    const int ho = tile >> 3;      // 0..63

    const int lane = t & 63, wid = t >> 6, quad = lane >> 4, l15 = lane & 15;
    const int gpos = t >> 2, gseg = t & 3;
    const int wo = gpos;
    const int spos = (ho << 6) + wo;
    const float* xb = xtf + ((size_t)b << 20);

    // A fragment base (ush): [step][hl][chunk=quad][oc][8], oc = wid*64 + i*16 + l15
    const unsigned short* aBase = bw2 + quad * 2048 + (((wid << 6) + l15) << 3);

    floatx4 acc[4][4];
#pragma unroll
    for (int i = 0; i < 4; i++)
#pragma unroll
        for (int j = 0; j < 4; j++) acc[i][j] = (floatx4){0.f, 0.f, 0.f, 0.f};

    // ---- prologue: all 9 taps' offset/mask -> 27 registers (loaded ONCE) ----
    float om0[9], om1[9], omm[9];
#pragma unroll
    for (int tp = 0; tp < 9; ++tp) {
        om0[tp] = offset[((size_t)(b * 18 + 2 * tp) << 12) + spos];
        om1[tp] = offset[((size_t)(b * 18 + 2 * tp + 1) << 12) + spos];
        omm[tp] = mask[((size_t)(b * 9 + tp) << 12) + spos];
    }

    half8 aCur[8], aNxt[8];        // [0..3]=hi rows, [4..7]=lo rows
    floatx4 crnA[8], crnB[8];      // in-phase corner double-buffer
    int yxs[2][4];                 // ping-pong coord sets (static-indexed)
    float wss[2][4];

#define MK(TP, S) do { mk_coords((TP), ho, wo, om0[TP], om1[TP], omm[TP],   \
        yxs[S][0], yxs[S][1], yxs[S][2], yxs[S][3],                         \
        wss[S][0], wss[S][1], wss[S][2], wss[S][3]); } while (0)

#define LOAD_CRN(DST, S, C) do {                                            \
    const int cb = ((C) << 5) + (gseg << 3);                                \
    const float* p00 = xb + ((size_t)yxs[S][0] << 8) + cb;                  \
    const float* p01 = xb + ((size_t)yxs[S][1] << 8) + cb;                  \
    const float* p10 = xb + ((size_t)yxs[S][2] << 8) + cb;                  \
    const float* p11 = xb + ((size_t)yxs[S][3] << 8) + cb;                  \
    DST[0] = *(const floatx4*)p00; DST[1] = *(const floatx4*)(p00 + 4);     \
    DST[2] = *(const floatx4*)p01; DST[3] = *(const floatx4*)(p01 + 4);     \
    DST[4] = *(const floatx4*)p10; DST[5] = *(const floatx4*)(p10 + 4);     \
    DST[6] = *(const floatx4*)p11; DST[7] = *(const floatx4*)(p11 + 4);     \
    } while (0)

#define GEN_WRITE(CRN, S, SLOT) do {                                        \
    float vals[8];                                                          \
    _Pragma("unroll")                                                       \
    for (int q = 0; q < 4; q++) {                                           \
        vals[q]     = wss[S][0] * CRN[0][q] + wss[S][1] * CRN[2][q] +       \
                      wss[S][2] * CRN[4][q] + wss[S][3] * CRN[6][q];        \
        vals[4 + q] = wss[S][0] * CRN[1][q] + wss[S][1] * CRN[3][q] +       \
                      wss[S][2] * CRN[5][q] + wss[S][3] * CRN[7][q];        \
    }                                                                       \
    uintx4 pkH, pkL;                                                        \
    split_pack8(vals, pkH, pkL);                                            \
    unsigned short* bp = Bs + (SLOT) * 4224 + gseg * 528 + (gpos << 3);     \
    *(uintx4*)bp = pkH;                                                     \
    *(uintx4*)(bp + 2112) = pkL;                                            \
    } while (0)

#define LOAD_A(DST, STEP) do {                                              \
    const unsigned short* ap = aBase + (size_t)(STEP) * 16384;              \
    _Pragma("unroll")                                                       \
    for (int i = 0; i < 4; i++) {                                           \
        DST[i]     = *(const half8*)(ap + i * 128);                         \
        DST[4 + i] = *(const half8*)(ap + 8192 + i * 128);                  \
    } } while (0)

#define MFMA_STEP(SLOT, AREG) do {                                          \
    const unsigned short* Bp = Bs + (SLOT) * 4224 + quad * 528;             \
    half8 bH[4], bL[4];                                                     \
    _Pragma("unroll")                                                       \
    for (int j = 0; j < 4; j++) {                                           \
        const int ro = ((j << 4) + l15) << 3;                               \
        bH[j] = *(const half8*)(Bp + ro);                                   \
        bL[j] = *(const half8*)(Bp + 2112 + ro);                            \
    }                                                                       \
    _Pragma("unroll")                                                       \
    for (int i = 0; i < 4; i++)                                             \
    _Pragma("unroll")                                                       \
        for (int j = 0; j < 4; j++) {                                       \
            acc[i][j] = MFMA16(AREG[i], bH[j], acc[i][j]);                  \
            acc[i][j] = MFMA16(AREG[4 + i], bH[j], acc[i][j]);              \
            acc[i][j] = MFMA16(AREG[i], bL[j], acc[i][j]);                  \
        } } while (0)

    for (int c = 0; c < 8; ++c) {   // runtime loop (keeps code size in I$)
        // ---- GEN phase: 9 taps at column-chunk c -> Bs[0..8] ----
        MK(0, 0);
        LOAD_CRN(crnA, 0, c);
#pragma unroll
        for (int tp = 0; tp < 9; ++tp) {
            if (tp < 8) {
                if ((tp & 1) == 0) { MK(tp + 1, 1); LOAD_CRN(crnB, 1, c); }
                else               { MK(tp + 1, 0); LOAD_CRN(crnA, 0, c); }
            }
            if ((tp & 1) == 0) GEN_WRITE(crnA, 0, tp);
            else               GEN_WRITE(crnB, 1, tp);
        }
        __syncthreads();                       // all Bs slots visible

        // ---- MFMA phase: 9 steps (step = tap*8 + c), A 1-deep in-phase ----
        LOAD_A(aCur, c);
#pragma unroll
        for (int tp = 0; tp < 9; ++tp) {
            if (tp < 8) {
                if ((tp & 1) == 0) LOAD_A(aNxt, (tp + 1) * 8 + c);
                else               LOAD_A(aCur, (tp + 1) * 8 + c);
            }
            if ((tp & 1) == 0) MFMA_STEP(tp, aCur);
            else               MFMA_STEP(tp, aNxt);
        }
        __syncthreads();                       // all reads done before next GEN
    }

    // ---- epilogue: C/D col=lane&15 -> pos, row=quad*4+r -> oc; undo x64 ----
    float* outb = out + ((size_t)b << 20);
    const int posbase = ho << 6;
#pragma unroll
    for (int i = 0; i < 4; i++) {
        const int ocb = (wid << 6) + (i << 4) + (quad << 2);
#pragma unroll
        for (int r = 0; r < 4; r++) {
            const float bv = bias[ocb + r];
#pragma unroll
            for (int j = 0; j < 4; j++) {
                const int pos = posbase + (j << 4) + l15;
                outb[((size_t)(ocb + r) << 12) + pos] = acc[i][j][r] * 0.015625f + bv;
            }
        }
    }
#undef MK
#undef LOAD_CRN
#undef GEN_WRITE
#undef LOAD_A
#undef MFMA_STEP
}

// ---- fallback (no workspace): R8-proven, unchanged ----
__global__ __launch_bounds__(256, 2) void k_dcn_fb(
    const float* __restrict__ x, const float* __restrict__ offset,
    const float* __restrict__ mask, const float* __restrict__ weight,
    const float* __restrict__ bias, float* __restrict__ out)
{
    __shared__ __align__(16) unsigned short AsH[256 * 40];
    __shared__ __align__(16) unsigned short AsL[256 * 40];
    __shared__ __align__(16) unsigned short BsH[64 * 40];
    __shared__ __align__(16) unsigned short BsL[64 * 40];
    __shared__ int cY[64][4];
    __shared__ float cW[64][4];

    const int t = threadIdx.x;
    const int tile = blockIdx.x;   // 512
    const int b = tile >> 6;
    const int ho = tile & 63;
    const int lane = t & 63, wid = t >> 6, quad = lane >> 4, l15 = lane & 15;
    const int gpos = t >> 2, gseg = t & 3;

    floatx4 acc[4][4];
#pragma unroll
    for (int i = 0; i < 4; i++)
#pragma unroll
        for (int j = 0; j < 4; j++) acc[i][j] = (floatx4){0.f, 0.f, 0.f, 0.f};

    for (int ktap = 0; ktap < 9; ++ktap) {
        __syncthreads();
        if (t < 64) {
            int wo = t;
            int spos = (ho << 6) + wo;
            float offy = offset[(((size_t)(b * 18 + 2 * ktap)) << 12) + spos];
            float offx = offset[(((size_t)(b * 18 + 2 * ktap + 1)) << 12) + spos];
            float m = mask[(((size_t)(b * 9 + ktap)) << 12) + spos];
            int c0, c1, c2, c3; float u0, u1, u2, u3;
            mk_coords(ktap, ho, wo, offy, offx, m, c0, c1, c2, c3, u0, u1, u2, u3);
            cY[t][0] = c0; cY[t][1] = c1; cY[t][2] = c2; cY[t][3] = c3;
            cW[t][0] = u0; cW[t][1] = u1; cW[t][2] = u2; cW[t][3] = u3;
        }
        __syncthreads();
        const int yx00 = cY[gpos][0], yx01 = cY[gpos][1];
        const int yx10 = cY[gpos][2], yx11 = cY[gpos][3];
        const float w00 = cW[gpos][0], w01 = cW[gpos][1];
        const float w10 = cW[gpos][2], w11 = cW[gpos][3];

        for (int cs = 0; cs < 8; ++cs) {
            const int c0 = cs << 5;
            {
                const float* wp = weight + (size_t)t * 2304 + (size_t)c0 * 9 + ktap;
#pragma unroll
                for (int kj = 0; kj < 32; kj += 2) {
                    unsigned int h0, l0u, h1, l1u;
                    split_f16_bits(wp[kj * 9] * 64.f, h0, l0u);
                    split_f16_bits(wp[kj * 9 + 9] * 64.f, h1, l1u);
                    *(unsigned int*)&AsH[t * 40 + kj] = h0 | (h1 << 16);
                    *(unsigned int*)&AsL[t * 40 + kj] = l0u | (l1u << 16);
                }
            }
            {
                const int cb = c0 + (gseg << 3);
                const float* xg = x + ((size_t)b << 20);
                float vals[8];
#pragma unroll
                for (int j = 0; j < 8; j++) {
                    const float* xc = xg + ((size_t)(cb + j) << 12);
                    vals[j] = w00 * xc[yx00] + w01 * xc[yx01] +
                              w10 * xc[yx10] + w11 * xc[yx11];
                }
                uintx4 pkH, pkL;
                split_pack8(vals, pkH, pkL);
                *(uintx4*)&BsH[gpos * 40 + (gseg << 3)] = pkH;
                *(uintx4*)&BsL[gpos * 40 + (gseg << 3)] = pkL;
            }
            __syncthreads();
            half8 aH[4], aL[4], bH[4], bL[4];
#pragma unroll
            for (int i = 0; i < 4; i++) {
                const int rowA = (wid << 6) + (i << 4) + l15;
                aH[i] = *(const half8*)&AsH[rowA * 40 + (quad << 3)];
                aL[i] = *(const half8*)&AsL[rowA * 40 + (quad << 3)];
            }
#pragma unroll
            for (int j = 0; j < 4; j++) {
                const int rowB = (j << 4) + l15;
                bH[j] = *(const half8*)&BsH[rowB * 40 + (quad << 3)];
                bL[j] = *(const half8*)&BsL[rowB * 40 + (quad << 3)];
            }
#pragma unroll
            for (int i = 0; i < 4; i++)
#pragma unroll
                for (int j = 0; j < 4; j++) {
                    acc[i][j] = MFMA16(aH[i], bH[j], acc[i][j]);
                    acc[i][j] = MFMA16(aL[i], bH[j], acc[i][j]);
                    acc[i][j] = MFMA16(aH[i], bL[j], acc[i][j]);
                }
            __syncthreads();
        }
    }
    float* outb = out + ((size_t)b << 20);
    const int posbase = ho << 6;
#pragma unroll
    for (int i = 0; i < 4; i++) {
        const int ocb = (wid << 6) + (i << 4) + (quad << 2);
#pragma unroll
        for (int r = 0; r < 4; r++) {
            const float bv = bias[ocb + r];
#pragma unroll
            for (int j = 0; j < 4; j++) {
                const int pos = posbase + (j << 4) + l15;
                outb[((size_t)(ocb + r) << 12) + pos] = acc[i][j][r] * 0.015625f + bv;
            }
        }
    }
}

extern "C" void kernel_launch(void* const* d_in, const int* in_sizes, int n_in,
                              void* d_out, int out_size, void* d_ws, size_t ws_size,
                              hipStream_t stream) {
    const float* x      = (const float*)d_in[0];
    const float* offset = (const float*)d_in[1];
    const float* mask   = (const float*)d_in[2];
    const float* weight = (const float*)d_in[3];
    const float* bias   = (const float*)d_in[4];
    float* out = (float*)d_out;

    const size_t xtf_bytes = (size_t)8 * 4096 * 256 * 4;       // 32 MB
    const size_t bw2_elems = (size_t)72 * 16384;               // 1179648 ush
    const size_t need = xtf_bytes + bw2_elems * 2;             // ~34.25 MB

    if (ws_size >= need) {
        float* xtf = (float*)d_ws;
        unsigned short* bw2 = (unsigned short*)((char*)d_ws + xtf_bytes);
        k_prep_xt<<<2048, 256, 0, stream>>>(x, xtf);
        k_prep_w2<<<(int)(bw2_elems / 256), 256, 0, stream>>>(weight, bw2);
        k_dcn_v11<<<512, 256, 0, stream>>>(offset, mask, bias, xtf, bw2, out);
    } else {
        k_dcn_fb<<<512, 256, 0, stream>>>(x, offset, mask, weight, bias, out);
    }
}

// Round 11
// 155.560 us; speedup vs baseline: 1.7206x; 1.4786x over previous
//
#include <hip/hip_runtime.h>
#include <stdint.h>

// DCNv2 fused forward (B=8, C=256, H=W=64, OC=256, 3x3, pad=1, stride=1, DG=1)
// R16 = R15 with the Bs layout bug fixed. R15 post-mortem: removing the hi/lo
// plane I wrongly halved the CHUNK STRIDE (528->264) — but a chunk is
// 64 pos x 8 ush = 512 ush, so chunks overlapped and corrupted each other
// (absmax 1.74 = data corruption, not numerics). Correct: stride 528 (proven),
// slot = 4*528 = 2112, Bs = 9*2112 = 38 KB.
// Structure (R14-proven): chunk-major phases, c=0..7; GEN 9 taps -> barrier ->
// 9 MFMA steps -> barrier. In-phase 1-deep pipelining only.
// Data plane (R15 theory, untested until now):
//  - xtfh fp16 (16 MB): corner chunk/row = 64 B = 1 line; 4 loads/tap.
//  - bw2 hi-only fp16 (1.15 MB): 4 A loads/step. Per-XCD set ~3.2 MB < L2.
//  - SINGLE-product fp16 GEMM (16 MFMA/step). Error budget vs 2^-8 gate:
//    per-term ~1.5*2^-11 rel, RMS ~1e-4, RTZ-bias ~2^-12*|out|, max ~6e-4.
//  - Weights x64 (subnormal guard), epilogue /64.

typedef __attribute__((ext_vector_type(8))) _Float16 half8;
typedef __attribute__((ext_vector_type(2))) __fp16 fp16x2;
typedef __attribute__((ext_vector_type(4))) float floatx4;
typedef __attribute__((ext_vector_type(4))) unsigned int uintx4;

#define MFMA16(A, B, C) __builtin_amdgcn_mfma_f32_16x16x32_f16(A, B, C, 0, 0, 0)

__device__ __forceinline__ unsigned short f16_bits_rne(float v) {
    _Float16 hf = (_Float16)v;               // v_cvt_f16_f32 (RNE)
    union { _Float16 f; unsigned short s; } a; a.f = hf;
    return a.s;
}

// pack 8 f32 -> 8 fp16 (4x cvt_pkrtz)
__device__ __forceinline__ void pack8(const float* vals, uintx4& pkH) {
#pragma unroll
    for (int p = 0; p < 4; p++) {
        fp16x2 h = __builtin_amdgcn_cvt_pkrtz(vals[2 * p], vals[2 * p + 1]);
        union { fp16x2 v; unsigned int u; } ch; ch.v = h;
        pkH[p] = ch.u;
    }
}

__device__ __forceinline__ void mk_coords(int tap, int ho, int wo,
    float offy, float offx, float m,
    int& yx00, int& yx01, int& yx10, int& yx11,
    float& w00, float& w01, float& w10, float& w11) {
    float py = (float)(tap / 3) + (float)(ho - 1) + offy;
    float px = (float)(tap % 3) + (float)(wo - 1) + offx;
    float y0f = floorf(py), x0f = floorf(px);
    float wy1 = py - y0f, wx1 = px - x0f;
    float wy0 = 1.f - wy1, wx0 = 1.f - wx1;
    int y0 = (int)y0f, x0 = (int)x0f, y1 = y0 + 1, x1 = x0 + 1;
    bool vy0 = (y0 >= 0) && (y0 < 64), vy1 = (y1 >= 0) && (y1 < 64);
    bool vx0 = (x0 >= 0) && (x0 < 64), vx1 = (x1 >= 0) && (x1 < 64);
    int cy0 = min(max(y0, 0), 63), cy1 = min(max(y1, 0), 63);
    int cx0 = min(max(x0, 0), 63), cx1 = min(max(x1, 0), 63);
    yx00 = cy0 * 64 + cx0; yx01 = cy0 * 64 + cx1;
    yx10 = cy1 * 64 + cx0; yx11 = cy1 * 64 + cx1;
    w00 = wy0 * wx0 * m * ((vy0 && vx0) ? 1.f : 0.f);
    w01 = wy0 * wx1 * m * ((vy0 && vx1) ? 1.f : 0.f);
    w10 = wy1 * wx0 * m * ((vy1 && vx0) ? 1.f : 0.f);
    w11 = wy1 * wx1 * m * ((vy1 && vx1) ? 1.f : 0.f);
}

// ---- prep: x (8,256,64,64) f32 -> xtfh (8,4096,256) fp16, tiled transpose ----
__global__ __launch_bounds__(256) void k_prep_xt(const float* __restrict__ x,
                                                 unsigned short* __restrict__ xtfh) {
    __shared__ float T[64][65];
    const int blk = blockIdx.x;       // 2048
    const int b = blk >> 8;
    const int ct = (blk >> 6) & 3;
    const int tt = blk & 63;
    const int t = threadIdx.x;
    const int jj = t & 63, i4 = t >> 6;
    const float* xb = x + ((size_t)b << 20);
#pragma unroll 4
    for (int ii = 0; ii < 16; ii++) {
        int i = ii * 4 + i4;
        T[i][jj] = xb[((size_t)(ct * 64 + i) << 12) + tt * 64 + jj];
    }
    __syncthreads();
    unsigned short* ob = xtfh + ((size_t)b << 20);
#pragma unroll 4
    for (int ii = 0; ii < 16; ii++) {
        int jo = ii * 4 + i4;
        ob[((size_t)(tt * 64 + jo) << 8) + ct * 64 + jj] = f16_bits_rne(T[jj][jo]);
    }
}

// ---- prep: weight*64 -> bw2[step72][chunk4][oc256][8k] fp16 (hi only) ----
__global__ __launch_bounds__(256) void k_prep_w2(const float* __restrict__ w,
                                                 unsigned short* __restrict__ bw2) {
    int tid = blockIdx.x * 256 + threadIdx.x;   // 72*8192 = 589824
    int j = tid & 7;
    int oc = (tid >> 3) & 255;
    int c = (tid >> 11) & 3;
    int step = tid >> 13;
    int ktap = step >> 3;
    int ch = ((step & 7) << 5) + (c << 3) + j;
    float v = w[oc * 2304 + ch * 9 + ktap] * 64.f;
    bw2[tid] = f16_bits_rne(v);
}

// ---- main (chunk-major phases, single-product fp16) ----
__global__ __launch_bounds__(256, 2) void k_dcn_v13(
    const float* __restrict__ offset,  // (8,18,64,64)
    const float* __restrict__ mask,    // (8,9,64,64)
    const float* __restrict__ bias,    // (256,)
    const unsigned short* __restrict__ xtfh, // (8,4096,256) fp16
    const unsigned short* __restrict__ bw2,  // (72,4,256,8) fp16
    float* __restrict__ out)           // (8,256,64,64)
{
    // B region: [slot9(tap)][chunk4(stride 528)][pos64][8]; slot = 2112 ush
    // (chunk = 64 pos x 8 ush = 512 + 16 pad = 528 — R14-PROVEN stride)
    __shared__ __align__(16) unsigned short Bs[9 * 2112];

    const int t = threadIdx.x;
    const int tile = blockIdx.x;   // 512
    const int b = tile & 7;        // XCD/L2 locality: each XCD sees ONE batch b
    const int ho = tile >> 3;      // 0..63

    const int lane = t & 63, wid = t >> 6, quad = lane >> 4, l15 = lane & 15;
    const int gpos = t >> 2, gseg = t & 3;
    const int wo = gpos;
    const int spos = (ho << 6) + wo;
    const unsigned short* xh = xtfh + ((size_t)b << 20);

    // A fragment base (ush): [step][chunk=quad][oc][8], oc = wid*64 + i*16 + l15
    const unsigned short* aBase = bw2 + quad * 2048 + (((wid << 6) + l15) << 3);

    floatx4 acc[4][4];
#pragma unroll
    for (int i = 0; i < 4; i++)
#pragma unroll
        for (int j = 0; j < 4; j++) acc[i][j] = (floatx4){0.f, 0.f, 0.f, 0.f};

    // ---- prologue: all 9 taps' offset/mask -> 27 registers (loaded ONCE) ----
    float om0[9], om1[9], omm[9];
#pragma unroll
    for (int tp = 0; tp < 9; ++tp) {
        om0[tp] = offset[((size_t)(b * 18 + 2 * tp) << 12) + spos];
        om1[tp] = offset[((size_t)(b * 18 + 2 * tp + 1) << 12) + spos];
        omm[tp] = mask[((size_t)(b * 9 + tp) << 12) + spos];
    }

    half8 aCur[4], aNxt[4];
    half8 crnA[4], crnB[4];        // 4 corners x 8 fp16 channels
    int yxs[2][4];                 // ping-pong coord sets (static-indexed)
    float wss[2][4];

#define MK(TP, S) do { mk_coords((TP), ho, wo, om0[TP], om1[TP], omm[TP],   \
        yxs[S][0], yxs[S][1], yxs[S][2], yxs[S][3],                         \
        wss[S][0], wss[S][1], wss[S][2], wss[S][3]); } while (0)

#define LOAD_CRN(DST, S, C) do {                                            \
    const int cb = ((C) << 5) + (gseg << 3);                                \
    DST[0] = *(const half8*)(xh + ((size_t)yxs[S][0] << 8) + cb);           \
    DST[1] = *(const half8*)(xh + ((size_t)yxs[S][1] << 8) + cb);           \
    DST[2] = *(const half8*)(xh + ((size_t)yxs[S][2] << 8) + cb);           \
    DST[3] = *(const half8*)(xh + ((size_t)yxs[S][3] << 8) + cb);           \
    } while (0)

#define GEN_WRITE(CRN, S, SLOT) do {                                        \
    float vals[8];                                                          \
    _Pragma("unroll")                                                       \
    for (int q = 0; q < 8; q++) {                                           \
        vals[q] = wss[S][0] * (float)CRN[0][q] + wss[S][1] * (float)CRN[1][q] \
                + wss[S][2] * (float)CRN[2][q] + wss[S][3] * (float)CRN[3][q];\
    }                                                                       \
    uintx4 pkH;                                                             \
    pack8(vals, pkH);                                                       \
    unsigned short* bp = Bs + (SLOT) * 2112 + gseg * 528 + (gpos << 3);     \
    *(uintx4*)bp = pkH;                                                     \
    } while (0)

#define LOAD_A(DST, STEP) do {                                              \
    const unsigned short* ap = aBase + (size_t)(STEP) * 8192;               \
    _Pragma("unroll")                                                       \
    for (int i = 0; i < 4; i++) DST[i] = *(const half8*)(ap + i * 128);     \
    } while (0)

#define MFMA_STEP(SLOT, AREG) do {                                          \
    const unsigned short* Bp = Bs + (SLOT) * 2112 + quad * 528;             \
    half8 bH[4];                                                            \
    _Pragma("unroll")                                                       \
    for (int j = 0; j < 4; j++)                                             \
        bH[j] = *(const half8*)(Bp + (((j << 4) + l15) << 3));              \
    _Pragma("unroll")                                                       \
    for (int i = 0; i < 4; i++)                                             \
    _Pragma("unroll")                                                       \
        for (int j = 0; j < 4; j++)                                         \
            acc[i][j] = MFMA16(AREG[i], bH[j], acc[i][j]);                  \
    } while (0)

    for (int c = 0; c < 8; ++c) {   // runtime loop (keeps code size in I$)
        // ---- GEN phase: 9 taps at column-chunk c -> Bs[0..8] ----
        MK(0, 0);
        LOAD_CRN(crnA, 0, c);
#pragma unroll
        for (int tp = 0; tp < 9; ++tp) {
            if (tp < 8) {
                if ((tp & 1) == 0) { MK(tp + 1, 1); LOAD_CRN(crnB, 1, c); }
                else               { MK(tp + 1, 0); LOAD_CRN(crnA, 0, c); }
            }
            if ((tp & 1) == 0) GEN_WRITE(crnA, 0, tp);
            else               GEN_WRITE(crnB, 1, tp);
        }
        __syncthreads();                       // all Bs slots visible

        // ---- MFMA phase: 9 steps (step = tap*8 + c), A 1-deep in-phase ----
        LOAD_A(aCur, c);
#pragma unroll
        for (int tp = 0; tp < 9; ++tp) {
            if (tp < 8) {
                if ((tp & 1) == 0) LOAD_A(aNxt, (tp + 1) * 8 + c);
                else               LOAD_A(aCur, (tp + 1) * 8 + c);
            }
            if ((tp & 1) == 0) MFMA_STEP(tp, aCur);
            else               MFMA_STEP(tp, aNxt);
        }
        __syncthreads();                       // all reads done before next GEN
    }

    // ---- epilogue: C/D col=lane&15 -> pos, row=quad*4+r -> oc; undo x64 ----
    float* outb = out + ((size_t)b << 20);
    const int posbase = ho << 6;
#pragma unroll
    for (int i = 0; i < 4; i++) {
        const int ocb = (wid << 6) + (i << 4) + (quad << 2);
#pragma unroll
        for (int r = 0; r < 4; r++) {
            const float bv = bias[ocb + r];
#pragma unroll
            for (int j = 0; j < 4; j++) {
                const int pos = posbase + (j << 4) + l15;
                outb[((size_t)(ocb + r) << 12) + pos] = acc[i][j][r] * 0.015625f + bv;
            }
        }
    }
#undef MK
#undef LOAD_CRN
#undef GEN_WRITE
#undef LOAD_A
#undef MFMA_STEP
}

// ---- fallback (no workspace): R8-proven 3-product path, unchanged ----
__device__ __forceinline__ void split_f16_bits(float v, unsigned int& h, unsigned int& l) {
    _Float16 hf = (_Float16)v;
    float hff = (float)hf;
    _Float16 lf = (_Float16)(v - hff);
    union { _Float16 f; unsigned short s; } a2, b2;
    a2.f = hf; b2.f = lf;
    h = a2.s; l = b2.s;
}
__device__ __forceinline__ void split_pack8(const float* vals, uintx4& pkH, uintx4& pkL) {
#pragma unroll
    for (int p = 0; p < 4; p++) {
        float v0 = vals[2 * p], v1 = vals[2 * p + 1];
        fp16x2 h = __builtin_amdgcn_cvt_pkrtz(v0, v1);
        float h0 = (float)h[0], h1 = (float)h[1];
        fp16x2 l = __builtin_amdgcn_cvt_pkrtz(v0 - h0, v1 - h1);
        union { fp16x2 v; unsigned int u; } ch, cl;
        ch.v = h; cl.v = l;
        pkH[p] = ch.u;
        pkL[p] = cl.u;
    }
}

__global__ __launch_bounds__(256, 2) void k_dcn_fb(
    const float* __restrict__ x, const float* __restrict__ offset,
    const float* __restrict__ mask, const float* __restrict__ weight,
    const float* __restrict__ bias, float* __restrict__ out)
{
    __shared__ __align__(16) unsigned short AsH[256 * 40];
    __shared__ __align__(16) unsigned short AsL[256 * 40];
    __shared__ __align__(16) unsigned short BsH[64 * 40];
    __shared__ __align__(16) unsigned short BsL[64 * 40];
    __shared__ int cY[64][4];
    __shared__ float cW[64][4];

    const int t = threadIdx.x;
    const int tile = blockIdx.x;   // 512
    const int b = tile >> 6;
    const int ho = tile & 63;
    const int lane = t & 63, wid = t >> 6, quad = lane >> 4, l15 = lane & 15;
    const int gpos = t >> 2, gseg = t & 3;

    floatx4 acc[4][4];
#pragma unroll
    for (int i = 0; i < 4; i++)
#pragma unroll
        for (int j = 0; j < 4; j++) acc[i][j] = (floatx4){0.f, 0.f, 0.f, 0.f};

    for (int ktap = 0; ktap < 9; ++ktap) {
        __syncthreads();
        if (t < 64) {
            int wo = t;
            int spos = (ho << 6) + wo;
            float offy = offset[(((size_t)(b * 18 + 2 * ktap)) << 12) + spos];
            float offx = offset[(((size_t)(b * 18 + 2 * ktap + 1)) << 12) + spos];
            float m = mask[(((size_t)(b * 9 + ktap)) << 12) + spos];
            int c0, c1, c2, c3; float u0, u1, u2, u3;
            mk_coords(ktap, ho, wo, offy, offx, m, c0, c1, c2, c3, u0, u1, u2, u3);
            cY[t][0] = c0; cY[t][1] = c1; cY[t][2] = c2; cY[t][3] = c3;
            cW[t][0] = u0; cW[t][1] = u1; cW[t][2] = u2; cW[t][3] = u3;
        }
        __syncthreads();
        const int yx00 = cY[gpos][0], yx01 = cY[gpos][1];
        const int yx10 = cY[gpos][2], yx11 = cY[gpos][3];
        const float w00 = cW[gpos][0], w01 = cW[gpos][1];
        const float w10 = cW[gpos][2], w11 = cW[gpos][3];

        for (int cs = 0; cs < 8; ++cs) {
            const int c0 = cs << 5;
            {
                const float* wp = weight + (size_t)t * 2304 + (size_t)c0 * 9 + ktap;
#pragma unroll
                for (int kj = 0; kj < 32; kj += 2) {
                    unsigned int h0, l0u, h1, l1u;
                    split_f16_bits(wp[kj * 9] * 64.f, h0, l0u);
                    split_f16_bits(wp[kj * 9 + 9] * 64.f, h1, l1u);
                    *(unsigned int*)&AsH[t * 40 + kj] = h0 | (h1 << 16);
                    *(unsigned int*)&AsL[t * 40 + kj] = l0u | (l1u << 16);
                }
            }
            {
                const int cb = c0 + (gseg << 3);
                const float* xg = x + ((size_t)b << 20);
                float vals[8];
#pragma unroll
                for (int j = 0; j < 8; j++) {
                    const float* xc = xg + ((size_t)(cb + j) << 12);
                    vals[j] = w00 * xc[yx00] + w01 * xc[yx01] +
                              w10 * xc[yx10] + w11 * xc[yx11];
                }
                uintx4 pkH, pkL;
                split_pack8(vals, pkH, pkL);
                *(uintx4*)&BsH[gpos * 40 + (gseg << 3)] = pkH;
                *(uintx4*)&BsL[gpos * 40 + (gseg << 3)] = pkL;
            }
            __syncthreads();
            half8 aH[4], aL[4], bH[4], bL[4];
#pragma unroll
            for (int i = 0; i < 4; i++) {
                const int rowA = (wid << 6) + (i << 4) + l15;
                aH[i] = *(const half8*)&AsH[rowA * 40 + (quad << 3)];
                aL[i] = *(const half8*)&AsL[rowA * 40 + (quad << 3)];
            }
#pragma unroll
            for (int j = 0; j < 4; j++) {
                const int rowB = (j << 4) + l15;
                bH[j] = *(const half8*)&BsH[rowB * 40 + (quad << 3)];
                bL[j] = *(const half8*)&BsL[rowB * 40 + (quad << 3)];
            }
#pragma unroll
            for (int i = 0; i < 4; i++)
#pragma unroll
                for (int j = 0; j < 4; j++) {
                    acc[i][j] = MFMA16(aH[i], bH[j], acc[i][j]);
                    acc[i][j] = MFMA16(aL[i], bH[j], acc[i][j]);
                    acc[i][j] = MFMA16(aH[i], bL[j], acc[i][j]);
                }
            __syncthreads();
        }
    }
    float* outb = out + ((size_t)b << 20);
    const int posbase = ho << 6;
#pragma unroll
    for (int i = 0; i < 4; i++) {
        const int ocb = (wid << 6) + (i << 4) + (quad << 2);
#pragma unroll
        for (int r = 0; r < 4; r++) {
            const float bv = bias[ocb + r];
#pragma unroll
            for (int j = 0; j < 4; j++) {
                const int pos = posbase + (j << 4) + l15;
                outb[((size_t)(ocb + r) << 12) + pos] = acc[i][j][r] * 0.015625f + bv;
            }
        }
    }
}

extern "C" void kernel_launch(void* const* d_in, const int* in_sizes, int n_in,
                              void* d_out, int out_size, void* d_ws, size_t ws_size,
                              hipStream_t stream) {
    const float* x      = (const float*)d_in[0];
    const float* offset = (const float*)d_in[1];
    const float* mask   = (const float*)d_in[2];
    const float* weight = (const float*)d_in[3];
    const float* bias   = (const float*)d_in[4];
    float* out = (float*)d_out;

    const size_t xtf_bytes = (size_t)8 * 4096 * 256 * 2;       // 16 MB fp16
    const size_t bw2_elems = (size_t)72 * 8192;                // 589824 ush
    const size_t need = xtf_bytes + bw2_elems * 2;             // ~17.1 MB

    if (ws_size >= need) {
        unsigned short* xtfh = (unsigned short*)d_ws;
        unsigned short* bw2 = (unsigned short*)((char*)d_ws + xtf_bytes);
        k_prep_xt<<<2048, 256, 0, stream>>>(x, xtfh);
        k_prep_w2<<<(int)(bw2_elems / 256), 256, 0, stream>>>(weight, bw2);
        k_dcn_v13<<<512, 256, 0, stream>>>(offset, mask, bias, xtfh, bw2, out);
    } else {
        k_dcn_fb<<<512, 256, 0, stream>>>(x, offset, mask, weight, bias, out);
    }
}

// Round 12
// 148.034 us; speedup vs baseline: 1.8081x; 1.0508x over previous
//
#include <hip/hip_runtime.h>
#include <stdint.h>

// DCNv2 fused forward (B=8, C=256, H=W=64, OC=256, 3x3, pad=1, stride=1, DG=1)
// R17 (v14): R16 (PROVEN: chunk-major phases, single-product fp16, stride-528
// Bs) restructured to 512-thread blocks for occupancy: 16 waves/CU (was ~6;
// Occupancy 19% was the binding constraint — all pipes < 26% busy).
//  - GEN: 9 taps split across two 256-thread groups (grp = t>>8, wave-uniform;
//    group g handles taps {2s+g}); per-group in-phase 1-deep corner pipeline.
//  - MFMA: 8 waves each own 32 oc (acc[2][4], 2 A loads/step, 8 MFMA/step).
//  - Preps fused into one grid-branched kernel (one less launch gap).
//  - All VMEM load->use within straight-line phase code (no backedge-carried
//    prefetch regs — R5/R10/R11 cursed pattern). om-prologue regs across
//    phases = R14/R16-proven safe.
// Numerics (R16-proven): xtfh fp16, bw2 hi-only fp16 x64, single-product
// fp16 MFMA, epilogue /64. Measured absmax 2^-7 vs 2.86e-2 gate.

typedef __attribute__((ext_vector_type(8))) _Float16 half8;
typedef __attribute__((ext_vector_type(2))) __fp16 fp16x2;
typedef __attribute__((ext_vector_type(4))) float floatx4;
typedef __attribute__((ext_vector_type(4))) unsigned int uintx4;

#define MFMA16(A, B, C) __builtin_amdgcn_mfma_f32_16x16x32_f16(A, B, C, 0, 0, 0)

__device__ __forceinline__ unsigned short f16_bits_rne(float v) {
    _Float16 hf = (_Float16)v;               // v_cvt_f16_f32 (RNE)
    union { _Float16 f; unsigned short s; } a; a.f = hf;
    return a.s;
}

// pack 8 f32 -> 8 fp16 (4x cvt_pkrtz)
__device__ __forceinline__ void pack8(const float* vals, uintx4& pkH) {
#pragma unroll
    for (int p = 0; p < 4; p++) {
        fp16x2 h = __builtin_amdgcn_cvt_pkrtz(vals[2 * p], vals[2 * p + 1]);
        union { fp16x2 v; unsigned int u; } ch; ch.v = h;
        pkH[p] = ch.u;
    }
}

__device__ __forceinline__ void mk_coords(int tap, int ho, int wo,
    float offy, float offx, float m,
    int& yx00, int& yx01, int& yx10, int& yx11,
    float& w00, float& w01, float& w10, float& w11) {
    float py = (float)(tap / 3) + (float)(ho - 1) + offy;
    float px = (float)(tap % 3) + (float)(wo - 1) + offx;
    float y0f = floorf(py), x0f = floorf(px);
    float wy1 = py - y0f, wx1 = px - x0f;
    float wy0 = 1.f - wy1, wx0 = 1.f - wx1;
    int y0 = (int)y0f, x0 = (int)x0f, y1 = y0 + 1, x1 = x0 + 1;
    bool vy0 = (y0 >= 0) && (y0 < 64), vy1 = (y1 >= 0) && (y1 < 64);
    bool vx0 = (x0 >= 0) && (x0 < 64), vx1 = (x1 >= 0) && (x1 < 64);
    int cy0 = min(max(y0, 0), 63), cy1 = min(max(y1, 0), 63);
    int cx0 = min(max(x0, 0), 63), cx1 = min(max(x1, 0), 63);
    yx00 = cy0 * 64 + cx0; yx01 = cy0 * 64 + cx1;
    yx10 = cy1 * 64 + cx0; yx11 = cy1 * 64 + cx1;
    w00 = wy0 * wx0 * m * ((vy0 && vx0) ? 1.f : 0.f);
    w01 = wy0 * wx1 * m * ((vy0 && vx1) ? 1.f : 0.f);
    w10 = wy1 * wx0 * m * ((vy1 && vx0) ? 1.f : 0.f);
    w11 = wy1 * wx1 * m * ((vy1 && vx1) ? 1.f : 0.f);
}

// ---- fused prep: blocks 0..2047 transpose x -> xtfh fp16;
//      blocks 2048..4351 weight*64 -> bw2 hi-only fp16 ----
__global__ __launch_bounds__(256) void k_prep(const float* __restrict__ x,
                                              const float* __restrict__ w,
                                              unsigned short* __restrict__ xtfh,
                                              unsigned short* __restrict__ bw2) {
    __shared__ float T[64][65];
    const int blk = blockIdx.x;
    const int t = threadIdx.x;
    if (blk < 2048) {
        const int b = blk >> 8;
        const int ct = (blk >> 6) & 3;
        const int tt = blk & 63;
        const int jj = t & 63, i4 = t >> 6;
        const float* xb = x + ((size_t)b << 20);
#pragma unroll 4
        for (int ii = 0; ii < 16; ii++) {
            int i = ii * 4 + i4;
            T[i][jj] = xb[((size_t)(ct * 64 + i) << 12) + tt * 64 + jj];
        }
        __syncthreads();
        unsigned short* ob = xtfh + ((size_t)b << 20);
#pragma unroll 4
        for (int ii = 0; ii < 16; ii++) {
            int jo = ii * 4 + i4;
            ob[((size_t)(tt * 64 + jo) << 8) + ct * 64 + jj] = f16_bits_rne(T[jj][jo]);
        }
    } else {
        int tid = (blk - 2048) * 256 + t;   // 72*8192 = 589824
        int j = tid & 7;
        int oc = (tid >> 3) & 255;
        int c = (tid >> 11) & 3;
        int step = tid >> 13;
        int ktap = step >> 3;
        int ch = ((step & 7) << 5) + (c << 3) + j;
        float v = w[oc * 2304 + ch * 9 + ktap] * 64.f;
        bw2[tid] = f16_bits_rne(v);
    }
}

// ---- main (512 threads, chunk-major phases, single-product fp16) ----
__global__ __launch_bounds__(512, 4) void k_dcn_v14(
    const float* __restrict__ offset,  // (8,18,64,64)
    const float* __restrict__ mask,    // (8,9,64,64)
    const float* __restrict__ bias,    // (256,)
    const unsigned short* __restrict__ xtfh, // (8,4096,256) fp16
    const unsigned short* __restrict__ bw2,  // (72,4,256,8) fp16
    float* __restrict__ out)           // (8,256,64,64)
{
    // B region: [slot9(tap)][chunk4(stride 528)][pos64][8]; slot = 2112 ush
    __shared__ __align__(16) unsigned short Bs[9 * 2112];

    const int t = threadIdx.x;         // 0..511
    const int tile = blockIdx.x;       // 512
    const int b = tile & 7;            // XCD/L2 locality
    const int ho = tile >> 3;          // 0..63

    const int lane = t & 63, w8 = t >> 6, quad = (t >> 4) & 3, l15 = t & 15;
    const int grp = t >> 8;            // GEN tap-group (wave-uniform)
    const int th = t & 255;
    const int gpos = th >> 2, gseg = th & 3;
    const int wo = gpos;
    const int spos = (ho << 6) + wo;
    const unsigned short* xh = xtfh + ((size_t)b << 20);

    // A fragment base: [step][chunk=quad][oc][8]; oc = w8*32 + i*16 + l15
    const unsigned short* aBase = bw2 + quad * 2048 + (((w8 << 5) + l15) << 3);

    floatx4 acc[2][4];
#pragma unroll
    for (int i = 0; i < 2; i++)
#pragma unroll
        for (int j = 0; j < 4; j++) acc[i][j] = (floatx4){0.f, 0.f, 0.f, 0.f};

    // ---- prologue: this group's 5 tap-slots of offset/mask (tap = 2s+grp,
    //      clamped; grp1 slot4 is a harmless dup of tap 8, write-guarded) ----
    float om0s[5], om1s[5], omms[5];
#pragma unroll
    for (int s = 0; s < 5; ++s) {
        int tap = 2 * s + grp; if (tap > 8) tap = 8;
        om0s[s] = offset[((size_t)(b * 18 + 2 * tap) << 12) + spos];
        om1s[s] = offset[((size_t)(b * 18 + 2 * tap + 1) << 12) + spos];
        omms[s] = mask[((size_t)(b * 9 + tap) << 12) + spos];
    }

    half8 aCur[2], aNxt[2];
    half8 crnA[4], crnB[4];        // 4 corners x 8 fp16 channels
    int yxs[2][4];                 // ping-pong coord sets (static-indexed)
    float wss[2][4];

#define MK(S, SET) do { int _tap = 2 * (S) + grp; if (_tap > 8) _tap = 8;   \
    mk_coords(_tap, ho, wo, om0s[S], om1s[S], omms[S],                      \
        yxs[SET][0], yxs[SET][1], yxs[SET][2], yxs[SET][3],                 \
        wss[SET][0], wss[SET][1], wss[SET][2], wss[SET][3]); } while (0)

#define LOAD_CRN(DST, SET, C) do {                                          \
    const int cb = ((C) << 5) + (gseg << 3);                                \
    DST[0] = *(const half8*)(xh + ((size_t)yxs[SET][0] << 8) + cb);         \
    DST[1] = *(const half8*)(xh + ((size_t)yxs[SET][1] << 8) + cb);         \
    DST[2] = *(const half8*)(xh + ((size_t)yxs[SET][2] << 8) + cb);         \
    DST[3] = *(const half8*)(xh + ((size_t)yxs[SET][3] << 8) + cb);         \
    } while (0)

#define GEN_WRITE(CRN, SET, SLOT) do {                                      \
    float vals[8];                                                          \
    _Pragma("unroll")                                                       \
    for (int q = 0; q < 8; q++) {                                           \
        vals[q] = wss[SET][0] * (float)CRN[0][q]                            \
                + wss[SET][1] * (float)CRN[1][q]                            \
                + wss[SET][2] * (float)CRN[2][q]                            \
                + wss[SET][3] * (float)CRN[3][q];                           \
    }                                                                       \
    uintx4 pkH;                                                             \
    pack8(vals, pkH);                                                       \
    unsigned short* bp = Bs + (SLOT) * 2112 + gseg * 528 + (gpos << 3);     \
    *(uintx4*)bp = pkH;                                                     \
    } while (0)

#define LOAD_A(DST, STEP) do {                                              \
    const unsigned short* ap = aBase + (size_t)(STEP) * 8192;               \
    DST[0] = *(const half8*)ap;                                             \
    DST[1] = *(const half8*)(ap + 128);                                     \
    } while (0)

#define MFMA_STEP(SLOT, AREG) do {                                          \
    const unsigned short* Bp = Bs + (SLOT) * 2112 + quad * 528;             \
    half8 bH[4];                                                            \
    _Pragma("unroll")                                                       \
    for (int j = 0; j < 4; j++)                                             \
        bH[j] = *(const half8*)(Bp + (((j << 4) + l15) << 3));              \
    _Pragma("unroll")                                                       \
    for (int i = 0; i < 2; i++)                                             \
    _Pragma("unroll")                                                       \
        for (int j = 0; j < 4; j++)                                         \
            acc[i][j] = MFMA16(AREG[i], bH[j], acc[i][j]);                  \
    } while (0)

    for (int c = 0; c < 8; ++c) {   // runtime loop (keeps code size in I$)
        // ---- GEN phase: group grp does taps {2s+grp} -> Bs slots ----
        MK(0, 0);
        LOAD_CRN(crnA, 0, c);
#pragma unroll
        for (int s = 0; s < 5; ++s) {
            if (s < 4) {
                if ((s & 1) == 0) { MK(s + 1, 1); LOAD_CRN(crnB, 1, c); }
                else              { MK(s + 1, 0); LOAD_CRN(crnA, 0, c); }
            }
            const int slot = 2 * s + grp;
            if (s < 4 || grp == 0) {           // tap 9 (grp1,s4) skipped
                if ((s & 1) == 0) GEN_WRITE(crnA, 0, slot);
                else              GEN_WRITE(crnB, 1, slot);
            }
        }
        __syncthreads();                       // all 9 Bs slots visible

        // ---- MFMA phase: 9 steps (step = tap*8 + c), A 1-deep in-phase ----
        LOAD_A(aCur, c);
#pragma unroll
        for (int tp = 0; tp < 9; ++tp) {
            if (tp < 8) {
                if ((tp & 1) == 0) LOAD_A(aNxt, (tp + 1) * 8 + c);
                else               LOAD_A(aCur, (tp + 1) * 8 + c);
            }
            if ((tp & 1) == 0) MFMA_STEP(tp, aCur);
            else               MFMA_STEP(tp, aNxt);
        }
        __syncthreads();                       // all reads done before next GEN
    }

    // ---- epilogue: C/D col=l15 -> pos, row=quad*4+r -> oc; undo x64 ----
    float* outb = out + ((size_t)b << 20);
    const int posbase = ho << 6;
#pragma unroll
    for (int i = 0; i < 2; i++) {
        const int ocb = (w8 << 5) + (i << 4) + (quad << 2);
#pragma unroll
        for (int r = 0; r < 4; r++) {
            const float bv = bias[ocb + r];
#pragma unroll
            for (int j = 0; j < 4; j++) {
                const int pos = posbase + (j << 4) + l15;
                outb[((size_t)(ocb + r) << 12) + pos] = acc[i][j][r] * 0.015625f + bv;
            }
        }
    }
#undef MK
#undef LOAD_CRN
#undef GEN_WRITE
#undef LOAD_A
#undef MFMA_STEP
}

// ---- fallback (no workspace): R8-proven 3-product path, unchanged ----
__device__ __forceinline__ void split_f16_bits(float v, unsigned int& h, unsigned int& l) {
    _Float16 hf = (_Float16)v;
    float hff = (float)hf;
    _Float16 lf = (_Float16)(v - hff);
    union { _Float16 f; unsigned short s; } a2, b2;
    a2.f = hf; b2.f = lf;
    h = a2.s; l = b2.s;
}
__device__ __forceinline__ void split_pack8(const float* vals, uintx4& pkH, uintx4& pkL) {
#pragma unroll
    for (int p = 0; p < 4; p++) {
        float v0 = vals[2 * p], v1 = vals[2 * p + 1];
        fp16x2 h = __builtin_amdgcn_cvt_pkrtz(v0, v1);
        float h0 = (float)h[0], h1 = (float)h[1];
        fp16x2 l = __builtin_amdgcn_cvt_pkrtz(v0 - h0, v1 - h1);
        union { fp16x2 v; unsigned int u; } ch, cl;
        ch.v = h; cl.v = l;
        pkH[p] = ch.u;
        pkL[p] = cl.u;
    }
}

__global__ __launch_bounds__(256, 2) void k_dcn_fb(
    const float* __restrict__ x, const float* __restrict__ offset,
    const float* __restrict__ mask, const float* __restrict__ weight,
    const float* __restrict__ bias, float* __restrict__ out)
{
    __shared__ __align__(16) unsigned short AsH[256 * 40];
    __shared__ __align__(16) unsigned short AsL[256 * 40];
    __shared__ __align__(16) unsigned short BsH[64 * 40];
    __shared__ __align__(16) unsigned short BsL[64 * 40];
    __shared__ int cY[64][4];
    __shared__ float cW[64][4];

    const int t = threadIdx.x;
    const int tile = blockIdx.x;   // 512
    const int b = tile >> 6;
    const int ho = tile & 63;
    const int lane = t & 63, wid = t >> 6, quad = lane >> 4, l15 = lane & 15;
    const int gpos = t >> 2, gseg = t & 3;

    floatx4 acc[4][4];
#pragma unroll
    for (int i = 0; i < 4; i++)
#pragma unroll
        for (int j = 0; j < 4; j++) acc[i][j] = (floatx4){0.f, 0.f, 0.f, 0.f};

    for (int ktap = 0; ktap < 9; ++ktap) {
        __syncthreads();
        if (t < 64) {
            int wo = t;
            int spos = (ho << 6) + wo;
            float offy = offset[(((size_t)(b * 18 + 2 * ktap)) << 12) + spos];
            float offx = offset[(((size_t)(b * 18 + 2 * ktap + 1)) << 12) + spos];
            float m = mask[(((size_t)(b * 9 + ktap)) << 12) + spos];
            int c0, c1, c2, c3; float u0, u1, u2, u3;
            mk_coords(ktap, ho, wo, offy, offx, m, c0, c1, c2, c3, u0, u1, u2, u3);
            cY[t][0] = c0; cY[t][1] = c1; cY[t][2] = c2; cY[t][3] = c3;
            cW[t][0] = u0; cW[t][1] = u1; cW[t][2] = u2; cW[t][3] = u3;
        }
        __syncthreads();
        const int yx00 = cY[gpos][0], yx01 = cY[gpos][1];
        const int yx10 = cY[gpos][2], yx11 = cY[gpos][3];
        const float w00 = cW[gpos][0], w01 = cW[gpos][1];
        const float w10 = cW[gpos][2], w11 = cW[gpos][3];

        for (int cs = 0; cs < 8; ++cs) {
            const int c0 = cs << 5;
            {
                const float* wp = weight + (size_t)t * 2304 + (size_t)c0 * 9 + ktap;
#pragma unroll
                for (int kj = 0; kj < 32; kj += 2) {
                    unsigned int h0, l0u, h1, l1u;
                    split_f16_bits(wp[kj * 9] * 64.f, h0, l0u);
                    split_f16_bits(wp[kj * 9 + 9] * 64.f, h1, l1u);
                    *(unsigned int*)&AsH[t * 40 + kj] = h0 | (h1 << 16);
                    *(unsigned int*)&AsL[t * 40 + kj] = l0u | (l1u << 16);
                }
            }
            {
                const int cb = c0 + (gseg << 3);
                const float* xg = x + ((size_t)b << 20);
                float vals[8];
#pragma unroll
                for (int j = 0; j < 8; j++) {
                    const float* xc = xg + ((size_t)(cb + j) << 12);
                    vals[j] = w00 * xc[yx00] + w01 * xc[yx01] +
                              w10 * xc[yx10] + w11 * xc[yx11];
                }
                uintx4 pkH, pkL;
                split_pack8(vals, pkH, pkL);
                *(uintx4*)&BsH[gpos * 40 + (gseg << 3)] = pkH;
                *(uintx4*)&BsL[gpos * 40 + (gseg << 3)] = pkL;
            }
            __syncthreads();
            half8 aH[4], aL[4], bH[4], bL[4];
#pragma unroll
            for (int i = 0; i < 4; i++) {
                const int rowA = (wid << 6) + (i << 4) + l15;
                aH[i] = *(const half8*)&AsH[rowA * 40 + (quad << 3)];
                aL[i] = *(const half8*)&AsL[rowA * 40 + (quad << 3)];
            }
#pragma unroll
            for (int j = 0; j < 4; j++) {
                const int rowB = (j << 4) + l15;
                bH[j] = *(const half8*)&BsH[rowB * 40 + (quad << 3)];
                bL[j] = *(const half8*)&BsL[rowB * 40 + (quad << 3)];
            }
#pragma unroll
            for (int i = 0; i < 4; i++)
#pragma unroll
                for (int j = 0; j < 4; j++) {
                    acc[i][j] = MFMA16(aH[i], bH[j], acc[i][j]);
                    acc[i][j] = MFMA16(aL[i], bH[j], acc[i][j]);
                    acc[i][j] = MFMA16(aH[i], bL[j], acc[i][j]);
                }
            __syncthreads();
        }
    }
    float* outb = out + ((size_t)b << 20);
    const int posbase = ho << 6;
#pragma unroll
    for (int i = 0; i < 4; i++) {
        const int ocb = (wid << 6) + (i << 4) + (quad << 2);
#pragma unroll
        for (int r = 0; r < 4; r++) {
            const float bv = bias[ocb + r];
#pragma unroll
            for (int j = 0; j < 4; j++) {
                const int pos = posbase + (j << 4) + l15;
                outb[((size_t)(ocb + r) << 12) + pos] = acc[i][j][r] * 0.015625f + bv;
            }
        }
    }
}

extern "C" void kernel_launch(void* const* d_in, const int* in_sizes, int n_in,
                              void* d_out, int out_size, void* d_ws, size_t ws_size,
                              hipStream_t stream) {
    const float* x      = (const float*)d_in[0];
    const float* offset = (const float*)d_in[1];
    const float* mask   = (const float*)d_in[2];
    const float* weight = (const float*)d_in[3];
    const float* bias   = (const float*)d_in[4];
    float* out = (float*)d_out;

    const size_t xtf_bytes = (size_t)8 * 4096 * 256 * 2;       // 16 MB fp16
    const size_t bw2_elems = (size_t)72 * 8192;                // 589824 ush
    const size_t need = xtf_bytes + bw2_elems * 2;             // ~17.1 MB

    if (ws_size >= need) {
        unsigned short* xtfh = (unsigned short*)d_ws;
        unsigned short* bw2 = (unsigned short*)((char*)d_ws + xtf_bytes);
        k_prep<<<2048 + 2304, 256, 0, stream>>>(x, weight, xtfh, bw2);
        k_dcn_v14<<<512, 512, 0, stream>>>(offset, mask, bias, xtfh, bw2, out);
    } else {
        k_dcn_fb<<<512, 256, 0, stream>>>(x, offset, mask, weight, bias, out);
    }
}